// Round 1
// baseline (29678.955 us; speedup 1.0000x reference)
//
#include <hip/hip_runtime.h>
#include <hip/hip_bf16.h>

// SSL-HSIC objective on MI355X.
// N=8192 rows, D=128, B=4096, M=2, GAMMA=3, SIGMA=1.
// Strategy: never materialize K. Upper-triangular 128x128 Gram tiles via
// bf16 MFMA (16x16x32), epilogue computes K=exp(min(dot-h_i-h_j,0)) and
// accumulates: S2=sum K^2, v[i]=row sums (atomics), diag, pos (|i-j|=4096).
// Final tiny kernel combines in fp64.

using bf16   = __bf16;
using bf16x8 = __attribute__((ext_vector_type(8))) __bf16;
using f32x4  = __attribute__((ext_vector_type(4))) float;

#define N_ROWS 8192
#define LOG2E  1.4426950408889634f

__device__ inline void atomicAddD(double* addr, double val) {
  unsigned long long* p = (unsigned long long*)addr;
  unsigned long long old = *p, assumed;
  do {
    assumed = old;
    old = atomicCAS(p, assumed,
                    __double_as_longlong(__longlong_as_double(assumed) + val));
  } while (old != assumed);
}

// ---------------------------------------------------------------- prep ----
// fp32 feat -> bf16 (RNE) into xb; h[row] = 0.5*sum(x^2) fp32;
// block 0 additionally zeroes v[8192] and the 4 scalar accumulators.
__global__ __launch_bounds__(256) void prep_kernel(
    const float* __restrict__ feat, unsigned short* __restrict__ xb,
    float* __restrict__ h, float* __restrict__ v, double* __restrict__ scal) {
  if (blockIdx.x == 0) {
    for (int i = threadIdx.x; i < N_ROWS; i += 256) v[i] = 0.f;
    if (threadIdx.x < 4) scal[threadIdx.x] = 0.0;
  }
  const int w = threadIdx.x >> 6, lane = threadIdx.x & 63;
  const int row = blockIdx.x * 4 + w;                  // one wave per row
  const float2 x2 = ((const float2*)feat)[row * 64 + lane];
  float ss = x2.x * x2.x + x2.y * x2.y;
#pragma unroll
  for (int m = 1; m < 64; m <<= 1) ss += __shfl_xor(ss, m);
  if (lane == 0) h[row] = 0.5f * ss;
  const unsigned int ux = __float_as_uint(x2.x);
  const unsigned int uy = __float_as_uint(x2.y);
  const unsigned short bx =
      (unsigned short)((ux + 0x7FFFu + ((ux >> 16) & 1u)) >> 16);
  const unsigned short by =
      (unsigned short)((uy + 0x7FFFu + ((uy >> 16) & 1u)) >> 16);
  ((ushort2*)xb)[row * 64 + lane] = make_ushort2(bx, by);
}

// ---------------------------------------------------------------- gram ----
// grid 64x64, upper triangle only (bj>=bi). 256 threads = 4 waves (2x2),
// each wave owns a 64x64 sub-tile = 4x4 fragments of 16x16, K=128 in 4 steps.
__global__ __launch_bounds__(256) void gram_kernel(
    const bf16* __restrict__ xb, const float* __restrict__ h,
    float* __restrict__ v, double* __restrict__ scal) {
  const int bi = blockIdx.x, bj = blockIdx.y;
  if (bj < bi) return;
  const int tid = threadIdx.x;
  const int lane = tid & 63;
  const int w = tid >> 6;
  const int wr = w >> 1, wc = w & 1;
  const int l15 = lane & 15, l4 = lane >> 4;
  const int arow0 = bi * 128 + wr * 64;   // A rows this wave covers
  const int brow0 = bj * 128 + wc * 64;   // B rows (= output cols)

  f32x4 acc[4][4] = {};

#pragma unroll
  for (int ks = 0; ks < 4; ++ks) {
    bf16x8 a[4], b[4];
#pragma unroll
    for (int f = 0; f < 4; ++f) {
      a[f] = *(const bf16x8*)(xb + (arow0 + f * 16 + l15) * 128 + ks * 32 + l4 * 8);
      b[f] = *(const bf16x8*)(xb + (brow0 + f * 16 + l15) * 128 + ks * 32 + l4 * 8);
    }
#pragma unroll
    for (int fr = 0; fr < 4; ++fr)
#pragma unroll
      for (int fc = 0; fc < 4; ++fc)
        acc[fr][fc] = __builtin_amdgcn_mfma_f32_16x16x32_bf16(
            a[fr], b[fc], acc[fr][fc], 0, 0, 0);
  }

  // ---- epilogue: K = exp(min(dot - h_i - h_j, 0)) and reductions ----
  const bool isdiag = (bi == bj);
  const bool ispos  = (bj - bi == 32);  // |i-j|==4096 lives only here

  float ha[4][4], hb[4];
#pragma unroll
  for (int fr = 0; fr < 4; ++fr)
#pragma unroll
    for (int e = 0; e < 4; ++e)
      ha[fr][e] = h[arow0 + fr * 16 + l4 * 4 + e];   // C-layout row
#pragma unroll
  for (int fc = 0; fc < 4; ++fc)
    hb[fc] = h[brow0 + fc * 16 + l15];               // C-layout col

  float rsum[4][4] = {};
  float csum[4] = {};
  float s2 = 0.f, pd = 0.f;

#pragma unroll
  for (int fr = 0; fr < 4; ++fr) {
#pragma unroll
    for (int fc = 0; fc < 4; ++fc) {
#pragma unroll
      for (int e = 0; e < 4; ++e) {
        const float dot = acc[fr][fc][e];
        const float me = fminf(dot - ha[fr][e] - hb[fc], 0.f);
        const float K = exp2f(me * LOG2E);
        s2 = fmaf(K, K, s2);
        rsum[fr][e] += K;
        csum[fc] += K;
        if (isdiag | ispos) {
          const int rr = wr * 64 + fr * 16 + l4 * 4 + e;
          const int cc = wc * 64 + fc * 16 + l15;
          pd += (rr == cc) ? K : 0.f;
        }
      }
    }
  }

  // row sums: reduce across the 16 col-lanes (same l>>4 group)
#pragma unroll
  for (int fr = 0; fr < 4; ++fr) {
#pragma unroll
    for (int e = 0; e < 4; ++e) {
      float r = rsum[fr][e];
      r += __shfl_xor(r, 1);
      r += __shfl_xor(r, 2);
      r += __shfl_xor(r, 4);
      r += __shfl_xor(r, 8);
      if (l15 == 0) atomicAdd(&v[arow0 + fr * 16 + l4 * 4 + e], r);
    }
  }
  // col sums (symmetric contribution) only for off-diagonal tiles
  if (!isdiag) {
#pragma unroll
    for (int fc = 0; fc < 4; ++fc) {
      float c = csum[fc];
      c += __shfl_xor(c, 16);
      c += __shfl_xor(c, 32);
      if (l4 == 0) atomicAdd(&v[brow0 + fc * 16 + l15], c);
    }
  }

  // scalar accumulators: wave-reduce then one atomic per wave
#pragma unroll
  for (int m = 1; m < 64; m <<= 1) s2 += __shfl_xor(s2, m);
  if (isdiag | ispos) {
#pragma unroll
    for (int m = 1; m < 64; m <<= 1) pd += __shfl_xor(pd, m);
  }
  if (lane == 0) {
    atomicAddD(&scal[0], (double)s2 * (isdiag ? 1.0 : 2.0));
    if (isdiag) atomicAddD(&scal[1], (double)pd);
    else if (ispos) atomicAddD(&scal[2], 2.0 * (double)pd);
  }
}

// --------------------------------------------------------------- final ----
__global__ __launch_bounds__(256) void final_kernel(
    const float* __restrict__ v, const double* __restrict__ scal,
    float* __restrict__ out) {
  const int tid = threadIdx.x;
  double t = 0.0, v2 = 0.0;
  for (int i = tid; i < N_ROWS; i += 256) {
    const double x = (double)v[i];
    t += x;
    v2 += x * x;
  }
#pragma unroll
  for (int m = 1; m < 64; m <<= 1) {
    t += __shfl_xor(t, m);
    v2 += __shfl_xor(v2, m);
  }
  __shared__ double sT[4], sV[4];
  const int w = tid >> 6, lane = tid & 63;
  if (lane == 0) { sT[w] = t; sV[w] = v2; }
  __syncthreads();
  if (tid == 0) {
    const double T  = sT[0] + sT[1] + sT[2] + sT[3];
    const double V2 = sV[0] + sV[1] + sV[2] + sV[3];
    const double S2 = scal[0], diag = scal[1], pos = scal[2];
    const double Nd = 8192.0, Bd = 4096.0;
    const double hzz = (S2 - (2.0 / Nd) * V2 + (T * T) / (Nd * Nd)) / (Nd * Nd);
    const double neg = (T - diag) - pos;
    const double t1 = pos / 8192.0;        // B*M*(M-1)
    const double t2 = neg / 67108864.0;    // B^2*M^2
    const double hzy = (Bd / (Bd - 1.0)) * (t1 - t2 - 1.0);
    out[0] = (float)(-hzy + 3.0 * sqrt(fmax(hzz, 0.0)));
  }
}

// -------------------------------------------------------------- launch ----
extern "C" void kernel_launch(void* const* d_in, const int* in_sizes, int n_in,
                              void* d_out, int out_size, void* d_ws,
                              size_t ws_size, hipStream_t stream) {
  (void)in_sizes; (void)n_in; (void)out_size; (void)ws_size;
  const float* feat = (const float*)d_in[0];
  char* ws = (char*)d_ws;
  // ws layout: xb 2MB | h 32KB | v 32KB | scal 32B  (total ~2.13 MB)
  unsigned short* xb = (unsigned short*)ws;
  float* h = (float*)(ws + 2097152);
  float* v = (float*)(ws + 2097152 + 32768);
  double* scal = (double*)(ws + 2097152 + 65536);
  float* out = (float*)d_out;

  prep_kernel<<<2048, 256, 0, stream>>>(feat, xb, h, v, scal);
  gram_kernel<<<dim3(64, 64), 256, 0, stream>>>((const bf16*)xb, h, v, scal);
  final_kernel<<<1, 256, 0, stream>>>(v, scal, out);
}

// Round 2
// 131.808 us; speedup vs baseline: 225.1683x; 225.1683x over previous
//
#include <hip/hip_runtime.h>
#include <hip/hip_bf16.h>

// SSL-HSIC on MI355X, round 2: atomic-free.
// N=8192, D=128, B=4096, M=2, GAMMA=3, SIGMA=1.
// K = exp(min(dot - h_i - h_j, 0)) with h = ||x||^2/2 (unit-ish rows).
// Needed reductions over K: T=sum, S2=sum K^2, V2=sum_i (row_i sum)^2,
// diag=sum K_ii, pos=sum_{|i-j|=4096} K_ij.
// Round-1 lesson: device-scope atomics serialize at the fabric (per-XCD L2
// non-coherent) -> 30ms of idle GPU. Now: per-block private partial slots,
// LDS-only cross-wave combining, fp64 only in the tiny final kernel.

using bf16   = __bf16;
using bf16x8 = __attribute__((ext_vector_type(8))) __bf16;
using f32x4  = __attribute__((ext_vector_type(4))) float;

#define N_ROWS 8192
#define LOG2E  1.4426950408889634f

// ---------------------------------------------------------------- prep ----
// fp32 feat -> bf16 (RNE) into xb; h[row] = 0.5*sum(x^2).
__global__ __launch_bounds__(256) void prep_kernel(
    const float* __restrict__ feat, unsigned short* __restrict__ xb,
    float* __restrict__ h) {
  const int w = threadIdx.x >> 6, lane = threadIdx.x & 63;
  const int row = blockIdx.x * 4 + w;  // one wave per row
  const float2 x2 = ((const float2*)feat)[row * 64 + lane];
  float ss = x2.x * x2.x + x2.y * x2.y;
#pragma unroll
  for (int m = 1; m < 64; m <<= 1) ss += __shfl_xor(ss, m);
  if (lane == 0) h[row] = 0.5f * ss;
  const unsigned int ux = __float_as_uint(x2.x);
  const unsigned int uy = __float_as_uint(x2.y);
  ushort2 o;
  o.x = (unsigned short)((ux + 0x7FFFu + ((ux >> 16) & 1u)) >> 16);
  o.y = (unsigned short)((uy + 0x7FFFu + ((uy >> 16) & 1u)) >> 16);
  ((ushort2*)xb)[row * 64 + lane] = o;
}

// ---------------------------------------------------------------- gram ----
// grid (8 col-chunks, 64 row-blocks). Block = 4 waves (2x2 over 128x128
// tile), loops over 8 column tiles. Full matrix (no triangular trick) so
// every reduction is block-private. No global atomics anywhere.
__global__ __launch_bounds__(256, 2) void gram_kernel(
    const bf16* __restrict__ xb, const float* __restrict__ h,
    float* __restrict__ rpart, float* __restrict__ bscal) {
  const int bjc = blockIdx.x, bi = blockIdx.y;
  const int tid = threadIdx.x, lane = tid & 63, w = tid >> 6;
  const int wr = w >> 1, wc = w & 1;
  const int l15 = lane & 15, l4 = lane >> 4;
  const int arow0 = bi * 128 + wr * 64;

  __shared__ float rbuf[128];
  __shared__ float sS[4], sD[4], sP[4];
  if (tid < 128) rbuf[tid] = 0.f;
  __syncthreads();

  // A fragments + row offsets: constant across the 8 column tiles -> hoist.
  bf16x8 a[4][4];  // [kstep][frag]
  float ha[4][4];  // [frag][e], C-layout rows
#pragma unroll
  for (int ks = 0; ks < 4; ++ks)
#pragma unroll
    for (int f = 0; f < 4; ++f)
      a[ks][f] =
          *(const bf16x8*)(xb + (arow0 + f * 16 + l15) * 128 + ks * 32 + l4 * 8);
#pragma unroll
  for (int fr = 0; fr < 4; ++fr)
#pragma unroll
    for (int e = 0; e < 4; ++e)
      ha[fr][e] = h[arow0 + fr * 16 + l4 * 4 + e];

  float rsum[4][4] = {};  // [fr][e] row-sum partials across all 8 tiles
  float s2 = 0.f, pdiag = 0.f, ppos = 0.f;

  for (int t = 0; t < 8; ++t) {
    const int bj = bjc * 8 + t;
    const int brow0 = bj * 128 + wc * 64;

    f32x4 acc[4][4] = {};
#pragma unroll
    for (int ks = 0; ks < 4; ++ks) {
      bf16x8 b[4];
#pragma unroll
      for (int f = 0; f < 4; ++f)
        b[f] = *(const bf16x8*)(xb + (brow0 + f * 16 + l15) * 128 + ks * 32 +
                                l4 * 8);
#pragma unroll
      for (int fr = 0; fr < 4; ++fr)
#pragma unroll
        for (int fc = 0; fc < 4; ++fc)
          acc[fr][fc] = __builtin_amdgcn_mfma_f32_16x16x32_bf16(
              a[ks][fr], b[fc], acc[fr][fc], 0, 0, 0);
    }

    float hb[4];
#pragma unroll
    for (int fc = 0; fc < 4; ++fc) hb[fc] = h[brow0 + fc * 16 + l15];

    const int dt = bj - bi;
    const bool isdiag = (dt == 0);
    const bool ispos = (dt == 32) || (dt == -32);

#pragma unroll
    for (int fr = 0; fr < 4; ++fr) {
#pragma unroll
      for (int fc = 0; fc < 4; ++fc) {
        const int cc = wc * 64 + fc * 16 + l15;
#pragma unroll
        for (int e = 0; e < 4; ++e) {
          const float dot = acc[fr][fc][e];
          const float me = fminf(dot - ha[fr][e] - hb[fc], 0.f);
          const float K = exp2f(me * LOG2E);
          s2 = fmaf(K, K, s2);
          rsum[fr][e] += K;
          if (isdiag | ispos) {
            const int rr = wr * 64 + fr * 16 + l4 * 4 + e;
            const float hit = (rr == cc) ? K : 0.f;
            if (isdiag) pdiag += hit;
            else ppos += hit;
          }
        }
      }
    }
  }

  // row sums: reduce over the 16 column-lanes, combine the two wc-waves in LDS
#pragma unroll
  for (int fr = 0; fr < 4; ++fr) {
#pragma unroll
    for (int e = 0; e < 4; ++e) {
      float r = rsum[fr][e];
      r += __shfl_xor(r, 1);
      r += __shfl_xor(r, 2);
      r += __shfl_xor(r, 4);
      r += __shfl_xor(r, 8);
      if (l15 == 0) atomicAdd(&rbuf[wr * 64 + fr * 16 + l4 * 4 + e], r);
    }
  }

  // scalar partials: wave reduce then LDS combine
#pragma unroll
  for (int m = 1; m < 64; m <<= 1) {
    s2 += __shfl_xor(s2, m);
    pdiag += __shfl_xor(pdiag, m);
    ppos += __shfl_xor(ppos, m);
  }
  if (lane == 0) { sS[w] = s2; sD[w] = pdiag; sP[w] = ppos; }
  __syncthreads();

  const int slot = bi * 8 + bjc;
  if (tid < 128) rpart[slot * 128 + tid] = rbuf[tid];
  if (tid == 0) {
    bscal[slot * 3 + 0] = sS[0] + sS[1] + sS[2] + sS[3];
    bscal[slot * 3 + 1] = sD[0] + sD[1] + sD[2] + sD[3];
    bscal[slot * 3 + 2] = sP[0] + sP[1] + sP[2] + sP[3];
  }
}

// --------------------------------------------------------------- final ----
__global__ __launch_bounds__(256) void final_kernel(
    const float* __restrict__ rpart, const float* __restrict__ bscal,
    float* __restrict__ out) {
  const int tid = threadIdx.x, lane = tid & 63, w = tid >> 6;
  double t = 0.0, v2 = 0.0, s2 = 0.0, dg = 0.0, ps = 0.0;
  for (int i = tid; i < N_ROWS; i += 256) {
    const int rb = i >> 7, r = i & 127;
    float s = 0.f;
#pragma unroll
    for (int c = 0; c < 8; ++c) s += rpart[(rb * 8 + c) * 128 + r];
    const double x = (double)s;
    t += x;
    v2 += x * x;
  }
  for (int i = tid; i < 512; i += 256) {
    s2 += (double)bscal[i * 3 + 0];
    dg += (double)bscal[i * 3 + 1];
    ps += (double)bscal[i * 3 + 2];
  }
#pragma unroll
  for (int m = 1; m < 64; m <<= 1) {
    t += __shfl_xor(t, m);
    v2 += __shfl_xor(v2, m);
    s2 += __shfl_xor(s2, m);
    dg += __shfl_xor(dg, m);
    ps += __shfl_xor(ps, m);
  }
  __shared__ double sh[5][4];
  if (lane == 0) {
    sh[0][w] = t; sh[1][w] = v2; sh[2][w] = s2; sh[3][w] = dg; sh[4][w] = ps;
  }
  __syncthreads();
  if (tid == 0) {
    const double T  = sh[0][0] + sh[0][1] + sh[0][2] + sh[0][3];
    const double V2 = sh[1][0] + sh[1][1] + sh[1][2] + sh[1][3];
    const double S2 = sh[2][0] + sh[2][1] + sh[2][2] + sh[2][3];
    const double DG = sh[3][0] + sh[3][1] + sh[3][2] + sh[3][3];
    const double PS = sh[4][0] + sh[4][1] + sh[4][2] + sh[4][3];
    const double Nd = 8192.0, Bd = 4096.0;
    const double hzz = (S2 - (2.0 / Nd) * V2 + (T * T) / (Nd * Nd)) / (Nd * Nd);
    const double neg = (T - DG) - PS;
    const double t1 = PS / 8192.0;       // B*M*(M-1)
    const double t2 = neg / 67108864.0;  // B^2*M^2
    const double hzy = (Bd / (Bd - 1.0)) * (t1 - t2 - 1.0);
    out[0] = (float)(-hzy + 3.0 * sqrt(fmax(hzz, 0.0)));
  }
}

// -------------------------------------------------------------- launch ----
extern "C" void kernel_launch(void* const* d_in, const int* in_sizes, int n_in,
                              void* d_out, int out_size, void* d_ws,
                              size_t ws_size, hipStream_t stream) {
  (void)in_sizes; (void)n_in; (void)out_size; (void)ws_size;
  const float* feat = (const float*)d_in[0];
  char* ws = (char*)d_ws;
  // ws: xb 2MB | h 32KB | rpart 256KB | bscal 6KB   (~2.29 MB total)
  unsigned short* xb = (unsigned short*)ws;
  float* h     = (float*)(ws + 2097152);
  float* rpart = (float*)(ws + 2097152 + 32768);
  float* bscal = (float*)(ws + 2097152 + 32768 + 262144);
  float* out = (float*)d_out;

  prep_kernel<<<2048, 256, 0, stream>>>(feat, xb, h);
  gram_kernel<<<dim3(8, 64), 256, 0, stream>>>((const bf16*)xb, h, rpart, bscal);
  final_kernel<<<1, 256, 0, stream>>>(rpart, bscal, out);
}